// Round 13
// baseline (174.116 us; speedup 1.0000x reference)
//
#include <hip/hip_runtime.h>
#include <math.h>

// DIAGNOSTIC ROUND: R12 kernel with per-element core x4 (REPS) to force the
// partial kernel above the 41us harness fills into the visible top-5 PMC rows.
// rep 0 -> acc (stored, output identical); reps 1-3 -> dummy (kept live via
// asm, rule #17); xv blinded per-rep ("+v" asm) so reps can't be CSE'd.
// Reads sought: SQ_LDS_BANK_CONFLICT (is the DS path real? conflict-bound?),
// VALUBusy (issue-bound?), OccupancyPercent, VGPR_Count.

constexpr int E_DIM = 128;
constexpr int N_DIM = 512;
constexpr int ST    = 8;     // s-rows per block
constexpr int TPB   = 256;   // threads per block (n-half)
constexpr int EC    = 4;     // e-chunks
constexpr int ECH   = E_DIM / EC;   // 32 e's per chunk
constexpr int REPS  = 4;     // diagnostic work multiplier

__global__ __launch_bounds__(TPB) void sin_layer_partial(
    const float* __restrict__ x,    // (B,S,E)
    const float* __restrict__ w,    // (E,N)
    const float* __restrict__ bv_,  // (E,N)
    const float* __restrict__ t,    // (S)
    float* __restrict__ part,       // (EC, B*S, N) partial sums
    int S, int BS)
{
    constexpr float SCALE4 = 4.0f * 512.0f * 0.15915493667125702f;
    constexpr float INV512 = 1.0f / 512.0f;

    __shared__ float lut[512];
    {
        const int tid = threadIdx.x;
#pragma unroll
        for (int j = 0; j < 512 / TPB; ++j) {
            const int i = j * TPB + tid;
            lut[i] = __builtin_amdgcn_sinf((float)i * INV512);  // sin(2pi*i/512)
        }
    }
    __syncthreads();

    const int bid = blockIdx.x;
    const int ec  = bid & (EC - 1);          // e-chunk
    const int nh  = (bid >> 2) & 1;          // n-half
    const int g   = bid >> 3;                // row group
    const int n   = nh * TPB + threadIdx.x;
    const int bs0 = g * ST;
    const int e0  = ec * ECH;

    float tn[ST];                             // wave-uniform
    float acc[ST];
    float dummy[ST];                          // reps 1..3 sink (kept live)
    const float* xr[ST];
#pragma unroll
    for (int i = 0; i < ST; ++i) {
        const int bs = bs0 + i;
        const int s  = (bs >= S) ? (bs - S) : bs;
        tn[i]  = t[s] * SCALE4;               // t in 4*bin units
        xr[i]  = x + (size_t)bs * E_DIM + e0;
        acc[i] = 0.0f;
        dummy[i] = 0.0f;
    }

    const float* wp = w   + (size_t)e0 * N_DIM + n;
    const float* bp = bv_ + (size_t)e0 * N_DIM + n;

#pragma unroll
    for (int rep = 0; rep < REPS; ++rep) {
#pragma unroll 4
        for (int e = 0; e < ECH; ++e) {
            const float wv = wp[(size_t)e * N_DIM];
            const float bb = bp[(size_t)e * N_DIM];
            const float wn4 = wv * SCALE4;        // w in 4*bin units
            float btn4[ST];
#pragma unroll
            for (int i = 0; i < ST; ++i)
                btn4[i] = __fmaf_rn(bb, SCALE4, tn[i]);   // (b+t) in 4*bin units
#pragma unroll
            for (int i = 0; i < ST; ++i) {
                float xv = xr[i][e];                   // wave-uniform
                asm volatile("" : "+v"(xv));           // opaque per rep: no CSE
                float u4 = __fmaf_rn(wn4, xv, btn4[i]);
                int  i4  = (int)floorf(u4);            // v_cvt_flr_i32_f32
                int  idx = (i4 & 2044) >> 2;           // (bin%512), byte-fold
                const float v = lut[idx];              // ds_read_b32
                if (rep == 0) acc[i]   += v;           // real result
                else          dummy[i] += v;           // blinded repeat
            }
        }
    }

#pragma unroll
    for (int i = 0; i < ST; ++i)
        asm volatile("" :: "v"(dummy[i]));    // keep rep-work live (rule #17)

    float* pp = part + (size_t)ec * BS * N_DIM;
#pragma unroll
    for (int i = 0; i < ST; ++i) {
        pp[(size_t)(bs0 + i) * N_DIM + n] = acc[i];
    }
}

__global__ __launch_bounds__(TPB) void sin_layer_reduce(
    const float* __restrict__ part,   // (EC, B*S*N) as float4
    float* __restrict__ out,          // (B*S*N)
    int nvec)                         // B*S*N/4
{
    const int i = blockIdx.x * TPB + threadIdx.x;
    if (i >= nvec) return;
    const float4* p = (const float4*)part;
    float4 a = p[i];
    float4 b = p[i + (size_t)nvec];
    float4 c = p[i + (size_t)2 * nvec];
    float4 d = p[i + (size_t)3 * nvec];
    float4 o;
    o.x = (a.x + b.x) + (c.x + d.x);
    o.y = (a.y + b.y) + (c.y + d.y);
    o.z = (a.z + b.z) + (c.z + d.z);
    o.w = (a.w + b.w) + (c.w + d.w);
    ((float4*)out)[i] = o;
}

extern "C" void kernel_launch(void* const* d_in, const int* in_sizes, int n_in,
                              void* d_out, int out_size, void* d_ws, size_t ws_size,
                              hipStream_t stream) {
    const float* x = (const float*)d_in[0];   // (B,S,E)
    const float* w = (const float*)d_in[1];   // (E,N)
    const float* b = (const float*)d_in[2];   // (E,N)
    const float* t = (const float*)d_in[3];   // (S)
    float* out  = (float*)d_out;              // (B*S*N)
    float* part = (float*)d_ws;               // (EC, B*S, N)

    const int S  = in_sizes[3];               // 1024
    const int BS = in_sizes[0] / E_DIM;       // 2048

    const int grid1 = (BS / ST) * 2 * EC;     // 256*2*4 = 2048 blocks
    sin_layer_partial<<<grid1, TPB, 0, stream>>>(x, w, b, t, part, S, BS);

    const int nvec  = out_size / 4;           // 262144
    const int grid2 = (nvec + TPB - 1) / TPB; // 1024 blocks
    sin_layer_reduce<<<grid2, TPB, 0, stream>>>(part, out, nvec);
}

// Round 14
// 96.242 us; speedup vs baseline: 1.8091x; 1.8091x over previous
//
#include <hip/hip_runtime.h>
#include <math.h>

// out[b,s,n] = sum_e SIN_TABLE[idx(w[e,n]*x[b,s,e] + b[e,n] + t[s])]
// B=2, S=1024, E=128, N=512, LUT_RES=512.
//
// Round-14: R13 diagnostic showed DS path engaged with 4.7 conflict-cyc per
// wave-read (random 64-lane gather into 32 banks). Fix: 32-way bank-major
// LUT replication (64 KB LDS) -> bank = lane&31 always, 2 lanes/bank = free.
// TPB=1024, RB=16 rows/block, 512 blocks -> 2 blocks/CU (64KB each), full
// 2048 thr/CU. Pre-scale by 65536/2pi (exact pow2 shift of the passing
// SCALE4) -> binning bit-identical to R12:
//   u   = fma(wn, x, btn)          (2^16*bin-units phase)
//   iu  = (int)floorf(u)
//   idx = ((iu & 65408) | co4)>>2  (bin*32 + lane&31; and_or+shr)
//   acc += lut32[idx]              (conflict-free ds_read_b32)

constexpr int E_DIM = 128;
constexpr int N_DIM = 512;
constexpr int EC    = 4;            // e-chunks
constexpr int ECH   = E_DIM / EC;   // 32 e's per chunk
constexpr int RB    = 16;           // rows per block
constexpr int RT    = 8;            // rows per thread
constexpr int TPB   = 1024;
constexpr int NCPY  = 32;           // LUT copies, one per bank

__global__ __launch_bounds__(TPB) void sin_layer_partial(
    const float* __restrict__ x,    // (B,S,E)
    const float* __restrict__ w,    // (E,N)
    const float* __restrict__ bv_,  // (E,N)
    const float* __restrict__ t,    // (S)
    float* __restrict__ part,       // (EC, B*S, N)
    int S, int BS)
{
    constexpr float SCALE128 = 65536.0f * 0.15915493667125702f; // exact *2^16
    constexpr float INV512   = 1.0f / 512.0f;

    __shared__ float lut32[512 * NCPY];   // 64 KB, bin-major, 32 copies/bin

    {
        const int tid = threadIdx.x;
#pragma unroll
        for (int k = 0; k < (512 * NCPY) / TPB; ++k) {
            const int j = tid + k * TPB;                  // consecutive -> 2-way write, free
            lut32[j] = __builtin_amdgcn_sinf((float)(j >> 5) * INV512);
        }
    }
    __syncthreads();

    const int bid = blockIdx.x;
    const int ec  = bid & (EC - 1);
    const int rg  = bid >> 2;             // row group (0..127)
    const int tid = threadIdx.x;
    const int n   = tid & (N_DIM - 1);
    const int rh  = tid >> 9;             // row half
    const int bs0 = rg * RB + rh * RT;
    const int e0  = ec * ECH;
    const int co4 = (tid & 31) << 2;      // replica byte offset (bank = lane&31)

    float tn[RT];
    float acc[RT];
    const float* xr[RT];
#pragma unroll
    for (int i = 0; i < RT; ++i) {
        const int bs = bs0 + i;
        const int s  = (bs >= S) ? (bs - S) : bs;
        tn[i]  = t[s] * SCALE128;         // t in 2^16*bin units
        xr[i]  = x + (size_t)bs * E_DIM + e0;
        acc[i] = 0.0f;
    }

    const float* wp = w   + (size_t)e0 * N_DIM + n;
    const float* bp = bv_ + (size_t)e0 * N_DIM + n;

#pragma unroll 4
    for (int e = 0; e < ECH; ++e) {
        const float wn = wp[(size_t)e * N_DIM] * SCALE128;
        const float bb = bp[(size_t)e * N_DIM];
        float btn[RT];
#pragma unroll
        for (int i = 0; i < RT; ++i)
            btn[i] = __fmaf_rn(bb, SCALE128, tn[i]);   // (b+t), 2^16*bin units
#pragma unroll
        for (int i = 0; i < RT; ++i) {
            const float xv = xr[i][e];                 // wave-uniform -> s_load
            const float u  = __fmaf_rn(wn, xv, btn[i]);
            const int   iu = (int)floorf(u);           // v_cvt_flr_i32_f32
            const int  idx = ((iu & 65408) | co4) >> 2; // bin*32 + (lane&31)
            acc[i] += lut32[idx];                      // conflict-free ds_read
        }
    }

    float* pp = part + (size_t)ec * BS * N_DIM;
#pragma unroll
    for (int i = 0; i < RT; ++i)
        pp[(size_t)(bs0 + i) * N_DIM + n] = acc[i];
}

__global__ __launch_bounds__(256) void sin_layer_reduce(
    const float* __restrict__ part,   // (EC, B*S*N) as float4
    float* __restrict__ out,          // (B*S*N)
    int nvec)                         // B*S*N/4
{
    const int i = blockIdx.x * 256 + threadIdx.x;
    if (i >= nvec) return;
    const float4* p = (const float4*)part;
    float4 a = p[i];
    float4 b = p[i + (size_t)nvec];
    float4 c = p[i + (size_t)2 * nvec];
    float4 d = p[i + (size_t)3 * nvec];
    float4 o;
    o.x = (a.x + b.x) + (c.x + d.x);
    o.y = (a.y + b.y) + (c.y + d.y);
    o.z = (a.z + b.z) + (c.z + d.z);
    o.w = (a.w + b.w) + (c.w + d.w);
    ((float4*)out)[i] = o;
}

extern "C" void kernel_launch(void* const* d_in, const int* in_sizes, int n_in,
                              void* d_out, int out_size, void* d_ws, size_t ws_size,
                              hipStream_t stream) {
    const float* x = (const float*)d_in[0];   // (B,S,E)
    const float* w = (const float*)d_in[1];   // (E,N)
    const float* b = (const float*)d_in[2];   // (E,N)
    const float* t = (const float*)d_in[3];   // (S)
    float* out  = (float*)d_out;              // (B*S*N)
    float* part = (float*)d_ws;               // (EC, B*S, N)

    const int S  = in_sizes[3];               // 1024
    const int BS = in_sizes[0] / E_DIM;       // 2048

    const int grid1 = (BS / RB) * EC;         // 128 * 4 = 512 blocks
    sin_layer_partial<<<grid1, TPB, 0, stream>>>(x, w, b, t, part, S, BS);

    const int nvec  = out_size / 4;           // 262144
    const int grid2 = (nvec + 255) / 256;     // 1024 blocks
    sin_layer_reduce<<<grid2, 256, 0, stream>>>(part, out, nvec);
}